// Round 5
// baseline (7049.083 us; speedup 1.0000x reference)
//
#include <hip/hip_runtime.h>

// ---------------- types ----------------
typedef _Float16 half8 __attribute__((ext_vector_type(8)));
typedef _Float16 half4v __attribute__((ext_vector_type(4)));
typedef float f32x4 __attribute__((ext_vector_type(4)));
typedef unsigned long long u64;

struct U128 { u64 a, b; };

#define B_ 64
#define T_ 512
#define H_ 1024
#define G_ 4096      // 4*H
#define K_ 1024

// ---------------- prep kernels ----------------
__global__ void k_f32_to_f16(const float* __restrict__ s, _Float16* __restrict__ d, int n4) {
  int i = blockIdx.x * 256 + threadIdx.x;
  if (i < n4) {
    float4 v = ((const float4*)s)[i];
    half4v o;
    o[0] = (_Float16)v.x; o[1] = (_Float16)v.y; o[2] = (_Float16)v.z; o[3] = (_Float16)v.w;
    ((half4v*)d)[i] = o;
  }
}

__global__ void k_bias(const float* __restrict__ bi0, const float* __restrict__ bh0,
                       const float* __restrict__ bi1, const float* __restrict__ bh1,
                       float* __restrict__ o0, float* __restrict__ o1) {
  int i = blockIdx.x * 256 + threadIdx.x;
  if (i < G_) { o0[i] = bi0[i] + bh0[i]; o1[i] = bi1[i] + bh1[i]; }
}

__global__ void k_zero(uint4* __restrict__ p, int n) {
  int i = blockIdx.x * 256 + threadIdx.x;
  if (i < n) p[i] = make_uint4(0u, 0u, 0u, 0u);
}

// ---------------- fused 2-layer persistent recurrence + in-kernel projection ----------------
// 256 WGs x 512 thr (cooperative), 1 WG/CU. Group g = blockIdx&3 owns batch rows
// [16g,16g+16); WG wid = blockIdx>>2 owns hidden units [16wid,16wid+16), BOTH layers.
// Iteration i: layer0 computes step i (i<T), layer1 computes step i-1 (i>=1).
//
// NEW (v6): the xg = X @ W_ih0 projection is computed IN-KERNEL, inside the
// publish->detect idle window of the previous iteration (lag 1; preamble does t=0).
// Per wave: gate gx=w&3, K-half kh=w>>2 -> xg partial [16m][16n] over K=512, with
// Wih0 fragments STREAMED from the WG's hot L2 (128 KB/WG/iter, plain cached loads)
// and X pre-converted to fp16. Only a 2-way partial sum (part_x) is read at finalize
// -> no extra reduce planes, no extra barriers. Eliminates the k_proj dispatch, the
// 256 MB xg HBM write and the ~450 MB xg read.
//
// Barrier: v5's parallel per-WG flag stores (single-writer, no RMW), wave0 polls
// all 64 flags coalesced, LDS relay to other waves.
__global__ __launch_bounds__(512) void k_fused(
    const _Float16* __restrict__ Xh,    // [B][T][K] fp16
    const _Float16* __restrict__ Wih0,  // [4H][K] fp16 (streamed per iteration)
    const _Float16* __restrict__ Whh0,  // [4H][K] fp16 (register resident)
    const _Float16* __restrict__ Wih1,  // [4H][K] fp16 (gates 0-1 regs, 2-3 LDS)
    const _Float16* __restrict__ Whh1,  // [4H][K] fp16 (register resident)
    const float* __restrict__ bias0,    // [4H] folded layer0 bias
    const float* __restrict__ bias1,    // [4H] folded layer1 bias
    _Float16* __restrict__ h0a, _Float16* __restrict__ h0b,  // layer0 h ping-pong
    _Float16* __restrict__ h1a, _Float16* __restrict__ h1b,  // layer1 h ping-pong
    unsigned int* flags,                // per-group 64 flags (128-dword stride)
    float* __restrict__ out32,          // d_out: out1 [B][T][H] fp32
    float* __restrict__ hn0, float* __restrict__ cn0,
    float* __restrict__ hn1, float* __restrict__ cn1) {
  int g = blockIdx.x & 3;
  int wid = blockIdx.x >> 2;
  int u0 = wid * 16;
  int bb = g * 16;                      // batch-row base of this group
  int tid = threadIdx.x;
  int lane = tid & 63, w = tid >> 6;
  int quad = lane >> 4, l16 = lane & 15;
  unsigned int* gf = flags + (g << 7);

  // planes 0-3: layer0 hh; planes 4-7: layer1. m-stride 18 -> <=2-way banks.
  __shared__ float part[8][8][16][18];            // 73728 B
  __shared__ float red[8][16][18];                // 9216 B
  __shared__ float part_x[4][2][16][17];          // 8704 B: xg partials [gate][K-half]
  __shared__ float cs[2][16][16];                 // 2048 B (cell states)
  __shared__ __align__(16) _Float16 wi1_lds[2 * 16 * 1032];  // 66048 B: Wih1 gates 2,3
  __shared__ int step_flag;
  ((float*)cs)[tid] = 0.f;              // 512 floats exactly
  if (tid == 0) step_flag = 0;

  // stage Wih1 gates 2-3 rows [u0,u0+16) into LDS (one-time)
  for (int idx = tid; idx < 2 * 16 * (K_ / 8); idx += 512) {
    int gt2 = idx >> 11;
    int r = (idx >> 7) & 15;
    int c = idx & 127;
    half8 v = *(const half8*)(Wih1 + (size_t)((2 + gt2) * H_ + u0 + r) * K_ + c * 8);
    *(half8*)(wi1_lds + (gt2 * 16 + r) * 1032 + c * 8) = v;
  }

  // resident weight fragments: wave w covers K-slice [128w, 128w+128)
  int ks = w * 128;
  half8 wf0[4][4], wh1[4][4], wi1r[2][4];
#pragma unroll
  for (int gt = 0; gt < 4; ++gt)
#pragma unroll
    for (int kk = 0; kk < 4; ++kk) {
      wf0[gt][kk] = *(const half8*)(Whh0 + (size_t)(gt * H_ + u0 + l16) * K_ + ks + kk * 32 + quad * 8);
      wh1[gt][kk] = *(const half8*)(Whh1 + (size_t)(gt * H_ + u0 + l16) * K_ + ks + kk * 32 + quad * 8);
    }
#pragma unroll
  for (int gt = 0; gt < 2; ++gt)
#pragma unroll
    for (int kk = 0; kk < 4; ++kk)
      wi1r[gt][kk] = *(const half8*)(Wih1 + (size_t)(gt * H_ + u0 + l16) * K_ + ks + kk * 32 + quad * 8);

  int fm = (w & 3) * 4 + quad;
  float b0v[4] = {}, b1v[4] = {};
  if (w < 4) {
#pragma unroll
    for (int gt = 0; gt < 4; ++gt) b0v[gt] = bias0[gt * H_ + u0 + l16];
  } else {
#pragma unroll
    for (int gt = 0; gt < 4; ++gt) b1v[gt] = bias1[gt * H_ + u0 + l16];
  }

  // xg window geometry: wave w -> gate gx, K-half kh (512 wide)
  int gx = w & 3, kh = w >> 2;
  const _Float16* wpB = Wih0 + (size_t)(gx * H_ + u0 + l16) * K_ + kh * 512 + quad * 8;
  const _Float16* xB0 = Xh + ((size_t)(bb + l16) * T_) * K_ + kh * 512 + quad * 8;

  // preamble: xg(0) into part_x
  {
    const _Float16* xB = xB0;  // t = 0
    f32x4 xcc = {};
#pragma unroll
    for (int kk = 0; kk < 16; ++kk) {
      half8 wv = *(const half8*)(wpB + kk * 32);
      half8 xv = *(const half8*)(xB + kk * 32);
      xcc = __builtin_amdgcn_mfma_f32_16x16x32_f16(xv, wv, xcc, 0, 0, 0);
    }
#pragma unroll
    for (int rr = 0; rr < 4; ++rr) part_x[gx][kh][quad * 4 + rr][l16] = xcc[rr];
  }
  __syncthreads();

  for (int i = 0; i <= T_; ++i) {
    const _Float16* h0r = (i & 1) ? h0b : h0a;
    _Float16* h0w = (i & 1) ? h0a : h0b;
    const _Float16* h1r = (i & 1) ? h1b : h1a;
    _Float16* h1w = (i & 1) ? h1a : h1b;

    // h0(i-1) fragments (feed L0-hh AND L1-ih) and h1(i-2) fragments (L1-hh)
    half8 af0[4], af1[4];
#pragma unroll
    for (int kk = 0; kk < 4; ++kk) {
      const _Float16* hs = h0r + (size_t)(bb + l16) * H_ + ks + kk * 32 + quad * 8;
      u64 qlo = __hip_atomic_load((const u64*)hs, __ATOMIC_RELAXED, __HIP_MEMORY_SCOPE_AGENT);
      u64 qhi = __hip_atomic_load(((const u64*)hs) + 1, __ATOMIC_RELAXED, __HIP_MEMORY_SCOPE_AGENT);
      U128 u; u.a = qlo; u.b = qhi;
      af0[kk] = __builtin_bit_cast(half8, u);
    }
#pragma unroll
    for (int kk = 0; kk < 4; ++kk) {
      const _Float16* hs = h1r + (size_t)(bb + l16) * H_ + ks + kk * 32 + quad * 8;
      u64 qlo = __hip_atomic_load((const u64*)hs, __ATOMIC_RELAXED, __HIP_MEMORY_SCOPE_AGENT);
      u64 qhi = __hip_atomic_load(((const u64*)hs) + 1, __ATOMIC_RELAXED, __HIP_MEMORY_SCOPE_AGENT);
      U128 u; u.a = qlo; u.b = qhi;
      af1[kk] = __builtin_bit_cast(half8, u);
    }

    // ---- layer0: acc = af0 x Whh0 ----
    {
      f32x4 acc[4] = {};
#pragma unroll
      for (int kk = 0; kk < 4; ++kk)
#pragma unroll
        for (int gt = 0; gt < 4; ++gt)
          acc[gt] = __builtin_amdgcn_mfma_f32_16x16x32_f16(af0[kk], wf0[gt][kk], acc[gt], 0, 0, 0);
#pragma unroll
      for (int gt = 0; gt < 4; ++gt)
#pragma unroll
        for (int rr = 0; rr < 4; ++rr)
          part[w][gt][quad * 4 + rr][l16] = acc[gt][rr];
    }
    // ---- layer1: bcc = af0 x Wih1 + af1 x Whh1 ----
    {
      f32x4 bcc[4] = {};
#pragma unroll
      for (int kk = 0; kk < 4; ++kk) {
        bcc[0] = __builtin_amdgcn_mfma_f32_16x16x32_f16(af0[kk], wi1r[0][kk], bcc[0], 0, 0, 0);
        bcc[1] = __builtin_amdgcn_mfma_f32_16x16x32_f16(af0[kk], wi1r[1][kk], bcc[1], 0, 0, 0);
        half8 w2 = *(const half8*)(wi1_lds + (0 * 16 + l16) * 1032 + ks + kk * 32 + quad * 8);
        bcc[2] = __builtin_amdgcn_mfma_f32_16x16x32_f16(af0[kk], w2, bcc[2], 0, 0, 0);
        half8 w3 = *(const half8*)(wi1_lds + (1 * 16 + l16) * 1032 + ks + kk * 32 + quad * 8);
        bcc[3] = __builtin_amdgcn_mfma_f32_16x16x32_f16(af0[kk], w3, bcc[3], 0, 0, 0);
      }
#pragma unroll
      for (int kk = 0; kk < 4; ++kk)
#pragma unroll
        for (int gt = 0; gt < 4; ++gt)
          bcc[gt] = __builtin_amdgcn_mfma_f32_16x16x32_f16(af1[kk], wh1[gt][kk], bcc[gt], 0, 0, 0);
#pragma unroll
      for (int gt = 0; gt < 4; ++gt)
#pragma unroll
        for (int rr = 0; rr < 4; ++rr)
          part[w][4 + gt][quad * 4 + rr][l16] = bcc[gt][rr];
    }
    __syncthreads();  // sync#1

    {  // cross-wave K reduction: wave w reduces plane w
#pragma unroll
      for (int rr = 0; rr < 4; ++rr) {
        int m = quad * 4 + rr;
        float sum = part[0][w][m][l16];
#pragma unroll
        for (int w2 = 1; w2 < 8; ++w2) sum += part[w2][w][m][l16];
        red[w][m][l16] = sum;
      }
    }
    __syncthreads();  // sync#2

    float ph = 0.f;        // deferred out1 value (waves 4-7)
    size_t poidx = 0;
    if (w < 4) {
      if (i < T_) {  // layer0 finalize, step i: hh-part (red) + xg (part_x) + bias
        int m = fm, n = l16;
        float iv = red[0][m][n] + part_x[0][0][m][n] + part_x[0][1][m][n] + b0v[0];
        float fv = red[1][m][n] + part_x[1][0][m][n] + part_x[1][1][m][n] + b0v[1];
        float gv = red[2][m][n] + part_x[2][0][m][n] + part_x[2][1][m][n] + b0v[2];
        float ov = red[3][m][n] + part_x[3][0][m][n] + part_x[3][1][m][n] + b0v[3];
        float si = 1.f / (1.f + __expf(-iv));
        float sf = 1.f / (1.f + __expf(-fv));
        float so = 1.f / (1.f + __expf(-ov));
        float ag = fabsf(gv), eg = __expf(-2.f * ag);
        float tg = (1.f - eg) / (1.f + eg);
        tg = (gv < 0.f) ? -tg : tg;
        float c = sf * cs[0][m][n] + si * tg;
        cs[0][m][n] = c;
        float ac = fabsf(c), ec = __expf(-2.f * ac);
        float th = (1.f - ec) / (1.f + ec);
        th = (c < 0.f) ? -th : th;
        float h = so * th;
        unsigned short hu = __builtin_bit_cast(unsigned short, (_Float16)h);
        unsigned other = __shfl_xor((unsigned)hu, 1, 64);
        if ((l16 & 1) == 0) {
          unsigned packed = (unsigned)hu | (other << 16);
          __hip_atomic_store((unsigned*)(h0w + (size_t)(bb + m) * H_ + u0 + l16), packed,
                             __ATOMIC_RELAXED, __HIP_MEMORY_SCOPE_AGENT);
        }
        if (i == T_ - 1) {
          hn0[(size_t)(bb + m) * H_ + u0 + n] = h;
          cn0[(size_t)(bb + m) * H_ + u0 + n] = c;
        }
      }
    } else {
      if (i >= 1) {  // layer1 finalize, step i-1
        int m = fm, n = l16;
        int j = i - 1;
        float iv = red[4][m][n] + b1v[0];
        float fv = red[5][m][n] + b1v[1];
        float gv = red[6][m][n] + b1v[2];
        float ov = red[7][m][n] + b1v[3];
        float si = 1.f / (1.f + __expf(-iv));
        float sf = 1.f / (1.f + __expf(-fv));
        float so = 1.f / (1.f + __expf(-ov));
        float ag = fabsf(gv), eg = __expf(-2.f * ag);
        float tg = (1.f - eg) / (1.f + eg);
        tg = (gv < 0.f) ? -tg : tg;
        float c = sf * cs[1][m][n] + si * tg;
        cs[1][m][n] = c;
        float ac = fabsf(c), ec = __expf(-2.f * ac);
        float th = (1.f - ec) / (1.f + ec);
        th = (c < 0.f) ? -th : th;
        float h = so * th;
        unsigned short hu = __builtin_bit_cast(unsigned short, (_Float16)h);
        unsigned other = __shfl_xor((unsigned)hu, 1, 64);
        if ((l16 & 1) == 0) {
          unsigned packed = (unsigned)hu | (other << 16);
          __hip_atomic_store((unsigned*)(h1w + (size_t)(bb + m) * H_ + u0 + l16), packed,
                             __ATOMIC_RELAXED, __HIP_MEMORY_SCOPE_AGENT);
        }
        ph = h;                              // defer HBM store past the publish
        poidx = ((size_t)(bb + m) * T_ + j) * H_ + u0 + n;
        if (j == T_ - 1) {
          hn1[(size_t)(bb + m) * H_ + u0 + n] = h;
          cn1[(size_t)(bb + m) * H_ + u0 + n] = c;
        }
      }
    }
    __syncthreads();  // sync#3: vmcnt(0) drain of the agent h stores

    if (i == T_) {
      if (w >= 4) out32[poidx] = ph;  // last deferred store (j = T_-1)
      break;
    }
    // publish: parallel single-writer flag store (no RMW)
    if (w == 1 && lane == 0)
      __hip_atomic_store(gf + wid, (unsigned)(i + 1),
                         __ATOMIC_RELAXED, __HIP_MEMORY_SCOPE_AGENT);
    // deferred out1 store: overlaps the spin
    if (w >= 4 && i >= 1) out32[poidx] = ph;

    // ---- idle-window work: compute xg(i+1) into part_x (overlaps flag flight/poll) ----
    if (i + 1 < T_) {
      const _Float16* xB = xB0 + (size_t)(i + 1) * K_;
      f32x4 xcc = {};
#pragma unroll
      for (int kk = 0; kk < 16; ++kk) {
        half8 wv = *(const half8*)(wpB + kk * 32);
        half8 xv = *(const half8*)(xB + kk * 32);
        xcc = __builtin_amdgcn_mfma_f32_16x16x32_f16(xv, wv, xcc, 0, 0, 0);
      }
#pragma unroll
      for (int rr = 0; rr < 4; ++rr) part_x[gx][kh][quad * 4 + rr][l16] = xcc[rr];
    }

    unsigned tgt = (unsigned)(i + 1);
    if (w == 0) {
      for (;;) {
        unsigned v = __hip_atomic_load(gf + lane, __ATOMIC_RELAXED, __HIP_MEMORY_SCOPE_AGENT);
        if (__all(v >= tgt)) break;
        __builtin_amdgcn_s_sleep(1);
      }
      asm volatile("" ::: "memory");  // block hoisting next iteration's loads
      if (lane == 0) __atomic_store_n(&step_flag, (int)tgt, __ATOMIC_RELEASE);
    } else {
      while (__atomic_load_n(&step_flag, __ATOMIC_ACQUIRE) < (int)tgt)
        __builtin_amdgcn_s_sleep(1);
      asm volatile("" ::: "memory");
    }
  }
}

// ---------------- host ----------------
extern "C" void kernel_launch(void* const* d_in, const int* in_sizes, int n_in,
                              void* d_out, int out_size, void* d_ws, size_t ws_size,
                              hipStream_t stream) {
  (void)in_sizes; (void)n_in; (void)out_size;
  const float* X    = (const float*)d_in[0];
  const float* Wih0 = (const float*)d_in[1];
  const float* bih0 = (const float*)d_in[2];
  const float* Whh0 = (const float*)d_in[3];
  const float* bhh0 = (const float*)d_in[4];
  const float* Wih1 = (const float*)d_in[5];
  const float* bih1 = (const float*)d_in[6];
  const float* Whh1 = (const float*)d_in[7];
  const float* bhh1 = (const float*)d_in[8];
  float* out = (float*)d_out;
  char* ws = (char*)d_ws;

  // ws layout (bytes):
  constexpr size_t SZW = (size_t)G_ * K_ * 2;  // 8 MB per packed weight
  constexpr size_t OFF_B0   = 4 * SZW;
  constexpr size_t OFF_B1   = OFF_B0 + 16384;
  constexpr size_t OFF_CNT  = OFF_B1 + 16384;          // flags (16KB reserved)
  constexpr size_t OFF_HBUF = OFF_CNT + 16384;         // 4 h buffers x 128KB
  constexpr size_t OFF_XH   = OFF_HBUF + 4 * 131072;   // X fp16: 64 MB
  constexpr size_t NEED     = OFF_XH + (size_t)B_ * T_ * K_ * 2;
  if (ws_size < NEED) return;  // fail visibly rather than corrupt

  _Float16* Wih0h = (_Float16*)(ws + 0 * SZW);
  _Float16* Whh0h = (_Float16*)(ws + 1 * SZW);
  _Float16* Wih1h = (_Float16*)(ws + 2 * SZW);
  _Float16* Whh1h = (_Float16*)(ws + 3 * SZW);
  float* b0s = (float*)(ws + OFF_B0);
  float* b1s = (float*)(ws + OFF_B1);
  unsigned int* flgs = (unsigned int*)(ws + OFF_CNT);
  _Float16* hb = (_Float16*)(ws + OFF_HBUF);
  _Float16* h0a = hb;
  _Float16* h0b = hb + 65536;
  _Float16* h1a = hb + 131072;
  _Float16* h1b = hb + 196608;
  _Float16* Xhp = (_Float16*)(ws + OFF_XH);

  // prep: pack weights + X to fp16, fold biases, zero flags + h buffers
  k_f32_to_f16<<<4096, 256, 0, stream>>>(Wih0, Wih0h, G_ * K_ / 4);
  k_f32_to_f16<<<4096, 256, 0, stream>>>(Whh0, Whh0h, G_ * K_ / 4);
  k_f32_to_f16<<<4096, 256, 0, stream>>>(Wih1, Wih1h, G_ * K_ / 4);
  k_f32_to_f16<<<4096, 256, 0, stream>>>(Whh1, Whh1h, G_ * K_ / 4);
  k_f32_to_f16<<<32768, 256, 0, stream>>>(X, Xhp, B_ * T_ * K_ / 4);
  k_bias<<<16, 256, 0, stream>>>(bih0, bhh0, bih1, bhh1, b0s, b1s);
  k_zero<<<132, 256, 0, stream>>>((uint4*)(ws + OFF_CNT), (int)((16384 + 4 * 131072) / 16));

  {
    const _Float16* a0 = Xhp;
    const _Float16* a1 = Wih0h;
    const _Float16* a2 = Whh0h;
    const _Float16* a3 = Wih1h;
    const _Float16* a4 = Whh1h;
    const float* a5 = b0s;
    const float* a6 = b1s;
    _Float16* a7 = h0a;
    _Float16* a8 = h0b;
    _Float16* a9 = h1a;
    _Float16* a10 = h1b;
    unsigned int* a11 = flgs;
    float* a12 = out;                               // out1 [B][T][H]
    float* a13 = out + 33554432;                    // h_n[0]
    float* a14 = out + 33554432 + 131072;           // c_n[0]
    float* a15 = out + 33554432 + 65536;            // h_n[1]
    float* a16 = out + 33554432 + 131072 + 65536;   // c_n[1]
    void* args[17] = {&a0, &a1, &a2, &a3, &a4, &a5, &a6, &a7, &a8,
                      &a9, &a10, &a11, &a12, &a13, &a14, &a15, &a16};
    hipLaunchCooperativeKernel((void*)k_fused, dim3(256), dim3(512), args, 0, stream);
  }
}